// Round 7
// baseline (182.442 us; speedup 1.0000x reference)
//
#include <hip/hip_runtime.h>
#include <hip/hip_bf16.h>
#include <math.h>

// AdaptedEntropyBottleneck on MI355X.
// Shapes: x [16,192,64,64] fp32, codebook [64] fp32 sorted, per-channel MLP
// 1->3->3->3->3->1 with softplus weights + tanh gates.
// Outputs: y_hat then lik, concatenated flat fp32 in d_out.
//
// v7: deepen memory-level parallelism in eb_main. Evidence: r0 (heavy binary
// search) and r6 (light LUT) both cost ~53 us -> not VALU/LDS bound; the
// shared trait was 1 outstanding x-load per thread (load->use->store loop).
// Now: one block per (n,c) slice (3072 blocks x 256 thr), ALL FOUR f32x4
// x-loads issued upfront (4x MLP), table/LUT staged while they fly, then
// compute + 8 stores. Element path = v6's bit-exact uniform-grid LUT
// (absmax was 0.0): LUT[b]=255 marks ambiguous bins -> exact slow path;
// else answer in {a,a+1} resolved by the reference strict-closer tie-break.

#define CCH 192
#define KCB 64
#define NBIN 2048

typedef float f32x4 __attribute__((ext_vector_type(4)));
typedef float f32x2 __attribute__((ext_vector_type(2)));

__device__ __forceinline__ float softplusf_(float x) {
    // jax.nn.softplus = logaddexp(x, 0) = max(x,0) + log1p(exp(-|x|))
    return fmaxf(x, 0.0f) + log1pf(expf(-fabsf(x)));
}
__device__ __forceinline__ float sigmoidf_(float x) {
    return 1.0f / (1.0f + expf(-x));
}

// Exact reference nearest-codebook: searchsorted(left) + strict-closer tie-break.
__device__ __forceinline__ int nearest_exact(const float* cb, float x) {
    int lo = 0, hi = 64;
    #pragma unroll
    for (int it = 0; it < 6; ++it) {
        const int mid = (lo + hi) >> 1;
        if (cb[mid] < x) lo = mid + 1; else hi = mid;
    }
    const int i  = lo;                 // insertion point in [0,64]
    int il = i - 1; il = (il < 0) ? 0 : il;
    const int ih = (i > 63) ? 63 : i;
    return (fabsf(cb[ih] - x) < fabsf(cb[il] - x)) ? ih : il;
}

// blocks 0..191: per-channel lik table (thread t: side=t>>6, k=t&63).
// blocks 192..199: uint8 nearest-LUT, 256 bins per block (2 per thread).
__global__ __launch_bounds__(128) void build_all(
        const float* __restrict__ cb,
        const float* __restrict__ m0, const float* __restrict__ b0, const float* __restrict__ f0,
        const float* __restrict__ m1, const float* __restrict__ b1, const float* __restrict__ f1,
        const float* __restrict__ m2, const float* __restrict__ b2, const float* __restrict__ f2,
        const float* __restrict__ m3, const float* __restrict__ b3, const float* __restrict__ f3,
        const float* __restrict__ m4, const float* __restrict__ b4,
        float* __restrict__ table, unsigned char* __restrict__ lut) {
    __shared__ float s_cb[KCB];
    __shared__ float s_side[128];
    const int tid = threadIdx.x;
    if (tid < 64) s_cb[tid] = cb[tid];
    __syncthreads();

    if (blockIdx.x < CCH) {
        const int c = blockIdx.x;
        const int k = tid & 63;
        const float v = s_cb[k] + ((tid < 64) ? -0.5f : 0.5f);

        float h0, h1, h2;
        {   // layer 0: (C,3,1) weights
            float z;
            z = softplusf_(m0[c * 3 + 0]) * v + b0[c * 3 + 0];
            z = z + tanhf(f0[c * 3 + 0]) * tanhf(z); h0 = z;
            z = softplusf_(m0[c * 3 + 1]) * v + b0[c * 3 + 1];
            z = z + tanhf(f0[c * 3 + 1]) * tanhf(z); h1 = z;
            z = softplusf_(m0[c * 3 + 2]) * v + b0[c * 3 + 2];
            z = z + tanhf(f0[c * 3 + 2]) * tanhf(z); h2 = z;
        }
        const float* Ms[3] = {m1, m2, m3};
        const float* Bs[3] = {b1, b2, b3};
        const float* Fs[3] = {f1, f2, f3};
        #pragma unroll
        for (int L = 0; L < 3; ++L) {
            const float* M = Ms[L];
            const float* B = Bs[L];
            const float* F = Fs[L];
            float n0, n1, n2;
            #pragma unroll
            for (int j = 0; j < 3; ++j) {
                float z = 0.0f;
                z += softplusf_(M[(c * 3 + j) * 3 + 0]) * h0;
                z += softplusf_(M[(c * 3 + j) * 3 + 1]) * h1;
                z += softplusf_(M[(c * 3 + j) * 3 + 2]) * h2;
                z += B[c * 3 + j];
                const float a = tanhf(F[c * 3 + j]);
                z = z + a * tanhf(z);
                if (j == 0) n0 = z; else if (j == 1) n1 = z; else n2 = z;
            }
            h0 = n0; h1 = n1; h2 = n2;
        }
        float res = 0.0f;
        res += softplusf_(m4[c * 3 + 0]) * h0;
        res += softplusf_(m4[c * 3 + 1]) * h1;
        res += softplusf_(m4[c * 3 + 2]) * h2;
        res += b4[c];
        s_side[tid] = res;
        __syncthreads();

        if (tid < 64) {
            const float lower = s_side[tid];
            const float upper = s_side[tid + 64];
            const float s  = lower + upper;
            const float sg = (s > 0.0f) ? -1.0f : ((s < 0.0f) ? 1.0f : 0.0f);
            float lik = fabsf(sigmoidf_(sg * upper) - sigmoidf_(sg * lower));
            table[c * 64 + tid] = fmaxf(lik, 1e-9f);
        }
    } else {
        // LUT blocks
        const float cbmin = s_cb[0], cbmax = s_cb[63];
        const float w = (cbmax - cbmin) / (float)NBIN;
        const float margin = 1e-4f;    // >> fp bin-rounding slop (~2.4e-6)
        const int bb = (blockIdx.x - CCH) * 256;
        #pragma unroll
        for (int r = 0; r < 2; ++r) {
            const int b = bb + r * 128 + tid;
            const float xs = cbmin + w * (float)b;
            const int ns = nearest_exact(s_cb, xs - margin);
            const int ne = nearest_exact(s_cb, xs + w + margin);
            lut[b] = (ne - ns <= 1) ? (unsigned char)ns : (unsigned char)255;
        }
    }
}

// One block = one (n,c) slice = 4096 elems = 1024 float4. 256 threads x 4 f32x4.
// All four x-loads issued before staging/sync -> 4 outstanding HBM loads/thread.
__global__ __launch_bounds__(256) void eb_main(
        const float* __restrict__ x,
        const float* __restrict__ cb,
        const float* __restrict__ table,
        const unsigned char* __restrict__ lut,
        float* __restrict__ out,
        int nvec) {
    __shared__ float s_cb[KCB];            // for rare exact slow path
    __shared__ f32x2 s_pair[KCB];          // {codebook value, lik}
    __shared__ unsigned char s_lut[NBIN];

    const int tid  = threadIdx.x;
    const int bid  = blockIdx.x;
    const int c    = bid % CCH;
    const int base4 = bid * 1024;          // float4 base index of this slice

    // ---- issue all x loads first: they stay in flight during staging
    const f32x4* xin = (const f32x4*)x;
    const f32x4 xv0 = xin[base4 + 0 * 256 + tid];
    const f32x4 xv1 = xin[base4 + 1 * 256 + tid];
    const f32x4 xv2 = xin[base4 + 2 * 256 + tid];
    const f32x4 xv3 = xin[base4 + 3 * 256 + tid];

    // ---- stage LUT (256 x 8B) and packed (cb,lik) pairs (threads 0..63)
    ((unsigned long long*)s_lut)[tid] = ((const unsigned long long*)lut)[tid];
    if (tid < 64) {
        const float cv = cb[tid];
        const float lk = table[c * 64 + tid];
        s_cb[tid] = cv;
        f32x2 p; p.x = cv; p.y = lk;
        s_pair[tid] = p;
    }
    __syncthreads();

    const float cbmin = s_cb[0];
    const float scale = (float)NBIN / (s_cb[63] - cbmin);

    f32x4 yo[4], lo4[4];
    #pragma unroll
    for (int half = 0; half < 4; ++half) {
        const f32x4 xv = (half == 0) ? xv0 : (half == 1) ? xv1
                        : (half == 2) ? xv2 : xv3;
        float xs_[4] = {xv.x, xv.y, xv.z, xv.w};
        float ys[4], ls[4];
        #pragma unroll
        for (int q = 0; q < 4; ++q) {
            const float xx = xs_[q];
            int bin = (int)((xx - cbmin) * scale);
            bin = bin < 0 ? 0 : (bin > NBIN - 1 ? NBIN - 1 : bin);
            int a = s_lut[bin];
            int idx_l, idx_h;
            if (__builtin_expect(a == 255, 0)) {
                // exact slow path (expected ~0.1% of elements)
                const int nn = nearest_exact(s_cb, xx);
                idx_l = nn; idx_h = nn;
            } else {
                idx_l = a;
                idx_h = (a + 1 > 63) ? 63 : a + 1;
            }
            const f32x2 pl = s_pair[idx_l];
            const f32x2 ph = s_pair[idx_h];
            // reference tie-break: pick hi iff strictly closer
            const bool pick_hi = fabsf(ph.x - xx) < fabsf(pl.x - xx);
            ys[q] = pick_hi ? ph.x : pl.x;
            ls[q] = pick_hi ? ph.y : pl.y;
        }
        yo[half].x  = ys[0]; yo[half].y  = ys[1]; yo[half].z  = ys[2]; yo[half].w  = ys[3];
        lo4[half].x = ls[0]; lo4[half].y = ls[1]; lo4[half].z = ls[2]; lo4[half].w = ls[3];
    }

    f32x4* yout = (f32x4*)out;
    #pragma unroll
    for (int half = 0; half < 4; ++half) {
        const int e4 = base4 + half * 256 + tid;
        yout[e4]        = yo[half];
        yout[nvec + e4] = lo4[half];
    }
}

extern "C" void kernel_launch(void* const* d_in, const int* in_sizes, int n_in,
                              void* d_out, int out_size, void* d_ws, size_t ws_size,
                              hipStream_t stream) {
    // setup_inputs dict order:
    // 0:x 1:codebook 2:m0 3:b0 4:f0 5:m1 6:b1 7:f1 8:m2 9:b2 10:f2
    // 11:m3 12:b3 13:f3 14:m4 15:b4
    const float* x  = (const float*)d_in[0];
    const float* cb = (const float*)d_in[1];
    const float* m0 = (const float*)d_in[2];
    const float* b0 = (const float*)d_in[3];
    const float* f0 = (const float*)d_in[4];
    const float* m1 = (const float*)d_in[5];
    const float* b1 = (const float*)d_in[6];
    const float* f1 = (const float*)d_in[7];
    const float* m2 = (const float*)d_in[8];
    const float* b2 = (const float*)d_in[9];
    const float* f2 = (const float*)d_in[10];
    const float* m3 = (const float*)d_in[11];
    const float* b3_ = (const float*)d_in[12];
    const float* f3 = (const float*)d_in[13];
    const float* m4 = (const float*)d_in[14];
    const float* b4 = (const float*)d_in[15];

    float* table = (float*)d_ws;                         // 12288 f32 = 48 KB
    unsigned char* lut = (unsigned char*)d_ws + 49152;   // 2048 u8

    build_all<<<CCH + 8, 128, 0, stream>>>(
        cb, m0, b0, f0, m1, b1, f1, m2, b2, f2, m3, b3_, f3, m4, b4,
        table, lut);

    const int total = in_sizes[0];         // 12,582,912 floats
    const int nvec  = total / 4;           // 3,145,728 float4s
    const int blocks = total / 4096;       // 3072 blocks: one (n,c) slice each

    eb_main<<<blocks, 256, 0, stream>>>(x, cb, table, lut, (float*)d_out, nvec);
}